// Round 1
// baseline (1273.098 us; speedup 1.0000x reference)
//
#include <hip/hip_runtime.h>
#include <math.h>

// Problem constants (from reference)
constexpr int B_ = 4;
constexpr int S_ = 2048;
constexpr int H_ = 16;
constexpr int HID_ = 2048;
constexpr int DK_ = 128;
constexpr int DV_ = 128;

// Scan tiling
constexpr int CH_ = 16;              // timesteps staged per LDS chunk
constexpr int NC_ = 4;               // DV split across blocks
constexpr int COLS_ = DV_ / NC_;     // 32 columns per block

// ---------------------------------------------------------------------------
// Kernel 1: gates. decay[b,s,h] = exp(-exp(A_log[h]) * softplus(x.Wa[h] + dt_bias[h]))
//           beta[b,s,h]  = x.Wb[h]
// One block per (b,s); wave w handles heads 4w..4w+3 (both Wa and Wb dots).
// ---------------------------------------------------------------------------
__global__ __launch_bounds__(256) void gates_kernel(
    const float* __restrict__ x, const float* __restrict__ Wa,
    const float* __restrict__ Wb, const float* __restrict__ dt_bias,
    const float* __restrict__ A_log, float* __restrict__ decay,
    float* __restrict__ beta) {
  const int bs = blockIdx.x;               // b*S + s
  const int wave = threadIdx.x >> 6;       // 0..3
  const int lane = threadIdx.x & 63;

  const float4* x4 = reinterpret_cast<const float4*>(x) + (size_t)bs * (HID_ / 4);
  const float4* Wa4 = reinterpret_cast<const float4*>(Wa);
  const float4* Wb4 = reinterpret_cast<const float4*>(Wb);

  float acc[8] = {0.f, 0.f, 0.f, 0.f, 0.f, 0.f, 0.f, 0.f};

  // HID/4 = 512 float4 per row; 64 lanes -> 8 iters
  for (int m = 0; m < (HID_ / 4) / 64; ++m) {
    const int d4 = m * 64 + lane;
    const float4 xv = x4[d4];
#pragma unroll
    for (int hh = 0; hh < 4; ++hh) {
      const int hd = (wave * 4 + hh) * (HID_ / 4) + d4;
      const float4 wa = Wa4[hd];
      const float4 wb = Wb4[hd];
      acc[hh] = fmaf(xv.x, wa.x, fmaf(xv.y, wa.y, fmaf(xv.z, wa.z, fmaf(xv.w, wa.w, acc[hh]))));
      acc[4 + hh] = fmaf(xv.x, wb.x, fmaf(xv.y, wb.y, fmaf(xv.z, wb.z, fmaf(xv.w, wb.w, acc[4 + hh]))));
    }
  }
  // full 64-lane reduction
#pragma unroll
  for (int off = 32; off >= 1; off >>= 1) {
#pragma unroll
    for (int a = 0; a < 8; ++a) acc[a] += __shfl_xor(acc[a], off, 64);
  }
  if (lane == 0) {
#pragma unroll
    for (int hh = 0; hh < 4; ++hh) {
      const int hidx = wave * 4 + hh;
      const float za = acc[hh] + dt_bias[hidx];
      // stable softplus
      const float sp = (za > 20.f) ? za : log1pf(expf(za));
      const float alpha = -expf(A_log[hidx]) * sp;
      decay[(size_t)bs * H_ + hidx] = expf(alpha);
      beta[(size_t)bs * H_ + hidx] = acc[4 + hh];
    }
  }
}

// ---------------------------------------------------------------------------
// Kernel 2: sequential delta-rule scan. Block = (dv-chunk c, head h, batch b).
// 256 threads; lane owns 16 rows x 1 col of the 128x32 state slice (registers).
// 8 consecutive lanes share a column -> shfl_xor(1,2,4) reductions.
// k/q/v/decay/beta staged in LDS per 16-step chunk, register-prefetched.
// ---------------------------------------------------------------------------
__global__ __launch_bounds__(256) void scan_kernel(
    const float* __restrict__ qg, const float* __restrict__ kg,
    const float* __restrict__ vg, const float* __restrict__ decay,
    const float* __restrict__ beta, float* __restrict__ outg) {
  const int c = blockIdx.x;   // DV chunk
  const int h = blockIdx.y;
  const int b = blockIdx.z;
  const int tid = threadIdx.x;
  const int sub = tid & 7;          // row-group within column (8 groups of 16 rows)
  const int colg = tid >> 3;        // 0..31 column within chunk
  const int col = c * COLS_ + colg;

  __shared__ __align__(16) float lk[CH_ * DK_];
  __shared__ __align__(16) float lq[CH_ * DK_];
  __shared__ __align__(16) float lv[CH_ * COLS_];
  __shared__ float lg[CH_];
  __shared__ float lb[CH_];

  const float4* k4 = reinterpret_cast<const float4*>(kg);
  const float4* q4 = reinterpret_cast<const float4*>(qg);
  const float4* v4 = reinterpret_cast<const float4*>(vg);
  float4* lk4 = reinterpret_cast<float4*>(lk);
  float4* lq4 = reinterpret_cast<float4*>(lq);
  float4* lv4 = reinterpret_cast<float4*>(lv);

  // Staging index map: 512 float4 per chunk for k (and q): idx -> (u = idx>>5, d4 = idx&31).
  // LDS physical slot is a transpose within the row: ph = (d4&3)*8 + (d4>>2),
  // so compute-phase reads lk4[u*32 + e*8 + sub] are 8 consecutive float4s (conflict-free).
  const int idx0 = tid, idx1 = 256 + tid;
  const int u0 = idx0 >> 5, d40 = idx0 & 31;
  const int u1 = idx1 >> 5, d41 = idx1 & 31;
  const int ph0 = u0 * 32 + (d40 & 3) * 8 + (d40 >> 2);
  const int ph1 = u1 * 32 + (d41 & 3) * 8 + (d41 >> 2);
  const size_t rowstride = (size_t)H_ * (DK_ / 4);  // float4 stride between timesteps

  float4 pk0 = {}, pk1 = {}, pq0 = {}, pq1 = {}, pv = {};
  float pg = 0.f, pb = 0.f;

  auto loadRegs = [&](int s0) {
    const size_t base = ((size_t)(b * S_ + s0) * H_ + h) * (DK_ / 4);
    pk0 = k4[base + (size_t)u0 * rowstride + d40];
    pk1 = k4[base + (size_t)u1 * rowstride + d41];
    pq0 = q4[base + (size_t)u0 * rowstride + d40];
    pq1 = q4[base + (size_t)u1 * rowstride + d41];
    if (tid < 128) {
      const int uu = tid >> 3, dd = tid & 7;
      pv = v4[base + (size_t)uu * rowstride + c * (COLS_ / 4) + dd];
    }
    if (tid >= 128 && tid < 128 + CH_)
      pg = decay[(size_t)(b * S_ + s0 + (tid - 128)) * H_ + h];
    if (tid >= 160 && tid < 160 + CH_)
      pb = beta[(size_t)(b * S_ + s0 + (tid - 160)) * H_ + h];
  };
  auto writeLDS = [&]() {
    lk4[ph0] = pk0; lk4[ph1] = pk1;
    lq4[ph0] = pq0; lq4[ph1] = pq1;
    if (tid < 128) { const int uu = tid >> 3, dd = tid & 7; lv4[uu * (COLS_ / 4) + dd] = pv; }
    if (tid >= 128 && tid < 128 + CH_) lg[tid - 128] = pg;
    if (tid >= 160 && tid < 160 + CH_) lb[tid - 160] = pb;
  };

  float st[16];
#pragma unroll
  for (int r = 0; r < 16; ++r) st[r] = 0.f;

  loadRegs(0);
  writeLDS();
  __syncthreads();

  constexpr int NCHS = S_ / CH_;  // 128 chunks
  for (int ci = 0; ci < NCHS; ++ci) {
    if (ci + 1 < NCHS) loadRegs((ci + 1) * CH_);  // prefetch next chunk (global)
    const int s0 = ci * CH_;

    for (int u = 0; u < CH_; ++u) {
      const float g = lg[u];
      const float bt = lb[u];
      const float vj = lv[u * COLS_ + colg];
      float kr[16], qr[16];
#pragma unroll
      for (int e = 0; e < 4; ++e) {
        const float4 kk = lk4[u * 32 + e * 8 + sub];
        const float4 qq = lq4[u * 32 + e * 8 + sub];
        kr[e * 4 + 0] = kk.x; kr[e * 4 + 1] = kk.y; kr[e * 4 + 2] = kk.z; kr[e * 4 + 3] = kk.w;
        qr[e * 4 + 0] = qq.x; qr[e * 4 + 1] = qq.y; qr[e * 4 + 2] = qq.z; qr[e * 4 + 3] = qq.w;
      }
      // v_old partial over my 16 rows (pre-decay state; decay folded in after)
      float vp0 = 0.f, vp1 = 0.f, vp2 = 0.f, vp3 = 0.f;
#pragma unroll
      for (int r = 0; r < 4; ++r) {
        vp0 = fmaf(kr[r], st[r], vp0);
        vp1 = fmaf(kr[4 + r], st[4 + r], vp1);
        vp2 = fmaf(kr[8 + r], st[8 + r], vp2);
        vp3 = fmaf(kr[12 + r], st[12 + r], vp3);
      }
      float vp = (vp0 + vp1) + (vp2 + vp3);
      vp += __shfl_xor(vp, 1, 64);
      vp += __shfl_xor(vp, 2, 64);
      vp += __shfl_xor(vp, 4, 64);
      const float dlt = (vj - g * vp) * bt;  // v_old = g * (k . s_prev)
      // state update: s = g*s_prev + k*dlt
#pragma unroll
      for (int r = 0; r < 16; ++r) st[r] = fmaf(kr[r], dlt, st[r] * g);
      // output dot
      float op0 = 0.f, op1 = 0.f, op2 = 0.f, op3 = 0.f;
#pragma unroll
      for (int r = 0; r < 4; ++r) {
        op0 = fmaf(qr[r], st[r], op0);
        op1 = fmaf(qr[4 + r], st[4 + r], op1);
        op2 = fmaf(qr[8 + r], st[8 + r], op2);
        op3 = fmaf(qr[12 + r], st[12 + r], op3);
      }
      float op = (op0 + op1) + (op2 + op3);
      op += __shfl_xor(op, 1, 64);
      op += __shfl_xor(op, 2, 64);
      op += __shfl_xor(op, 4, 64);
      if (sub == 0)
        outg[((size_t)(b * S_ + s0 + u) * H_ + h) * DV_ + col] = op;
    }

    __syncthreads();                     // all lanes done reading this chunk's LDS
    if (ci + 1 < NCHS) writeLDS();       // commit prefetched chunk
    __syncthreads();                     // LDS ready for next chunk
  }
}

extern "C" void kernel_launch(void* const* d_in, const int* in_sizes, int n_in,
                              void* d_out, int out_size, void* d_ws, size_t ws_size,
                              hipStream_t stream) {
  const float* x = (const float*)d_in[0];
  const float* q = (const float*)d_in[1];
  const float* k = (const float*)d_in[2];
  const float* v = (const float*)d_in[3];
  const float* Wa = (const float*)d_in[4];
  const float* Wb = (const float*)d_in[5];
  const float* dtb = (const float*)d_in[6];
  const float* Alog = (const float*)d_in[7];
  float* out = (float*)d_out;

  float* decay = (float*)d_ws;                 // B*S*H floats
  float* beta = decay + (size_t)B_ * S_ * H_;  // B*S*H floats

  gates_kernel<<<B_ * S_, 256, 0, stream>>>(x, Wa, Wb, dtb, Alog, decay, beta);
  scan_kernel<<<dim3(NC_, H_, B_), 256, 0, stream>>>(q, k, v, decay, beta, out);
}

// Round 2
// 834.302 us; speedup vs baseline: 1.5259x; 1.5259x over previous
//
#include <hip/hip_runtime.h>
#include <math.h>

constexpr int B_ = 4;
constexpr int S_ = 2048;
constexpr int H_ = 16;
constexpr int HID_ = 2048;
constexpr int DK_ = 128;
constexpr int DV_ = 128;

constexpr int CH_ = 16;              // timesteps per LDS chunk
constexpr int NC_ = 4;               // DV split across blocks
constexpr int COLS_ = DV_ / NC_;     // 32 columns per block
constexpr int NCHS_ = S_ / CH_;      // 128 chunks

// ---------------- DPP cross-lane helpers (VALU-latency, no DS pipe) --------
template <int CTRL>
__device__ __forceinline__ float dpp_add(float x) {
  int y = __builtin_amdgcn_update_dpp(0, __float_as_int(x), CTRL, 0xF, 0xF, true);
  return x + __int_as_float(y);
}
// butterfly sum over aligned 16-lane groups; every lane gets the total
__device__ __forceinline__ float sum16(float x) {
  x = dpp_add<0xB1>(x);   // quad_perm [1,0,3,2]  (xor 1)
  x = dpp_add<0x4E>(x);   // quad_perm [2,3,0,1]  (xor 2)
  x = dpp_add<0x141>(x);  // row_half_mirror      (xor 7)
  x = dpp_add<0x140>(x);  // row_mirror           (xor 15)
  return x;
}
__device__ __forceinline__ float swz_xor16(float x) {
  // BitMode swizzle: lane ^= 16 within each 32-lane group
  int y = __builtin_amdgcn_ds_swizzle(__float_as_int(x), 0x401F);
  return __int_as_float(y);
}

// ---------------------------------------------------------------------------
// Gates: decay/beta for all (b,s,h). Block = 4 rows of BS; wave w covers 8
// output cols (waves 0,1 -> Wa heads 0-7/8-15; waves 2,3 -> Wb heads 0-7/8-15).
// Register tile 4 rows x 8 cols per lane, K split across 64 lanes.
// ---------------------------------------------------------------------------
__global__ __launch_bounds__(256) void gates_kernel(
    const float* __restrict__ x, const float* __restrict__ Wa,
    const float* __restrict__ Wb, const float* __restrict__ dt_bias,
    const float* __restrict__ A_log, float* __restrict__ decay,
    float* __restrict__ beta) {
  const int r0 = blockIdx.x * 4;
  const int w = threadIdx.x >> 6;
  const int lane = threadIdx.x & 63;

  const float4* x4 = reinterpret_cast<const float4*>(x);
  const float4* wbase = reinterpret_cast<const float4*>(w < 2 ? Wa : Wb);
  const int h0 = (w & 1) * 8;

  float acc[4][8];
#pragma unroll
  for (int i = 0; i < 4; ++i)
#pragma unroll
    for (int j = 0; j < 8; ++j) acc[i][j] = 0.f;

  for (int m = 0; m < 8; ++m) {
    const int kk = m * 64 + lane;
    float4 xv[4], wv[8];
#pragma unroll
    for (int i = 0; i < 4; ++i) xv[i] = x4[(size_t)(r0 + i) * (HID_ / 4) + kk];
#pragma unroll
    for (int j = 0; j < 8; ++j) wv[j] = wbase[(size_t)(h0 + j) * (HID_ / 4) + kk];
#pragma unroll
    for (int i = 0; i < 4; ++i)
#pragma unroll
      for (int j = 0; j < 8; ++j) {
        acc[i][j] = fmaf(xv[i].x, wv[j].x, acc[i][j]);
        acc[i][j] = fmaf(xv[i].y, wv[j].y, acc[i][j]);
        acc[i][j] = fmaf(xv[i].z, wv[j].z, acc[i][j]);
        acc[i][j] = fmaf(xv[i].w, wv[j].w, acc[i][j]);
      }
  }

  float myval = 0.f;
#pragma unroll
  for (int i = 0; i < 4; ++i)
#pragma unroll
    for (int j = 0; j < 8; ++j) {
      float v = sum16(acc[i][j]);
      v += __shfl_xor(v, 16, 64);
      v += __shfl_xor(v, 32, 64);
      if (lane == i * 8 + j) myval = v;
    }
  if (lane < 32) {
    const int i = lane >> 3, j = lane & 7;
    const int h = h0 + j;
    const int row = r0 + i;
    if (w < 2) {
      const float za = myval + dt_bias[h];
      const float sp = (za > 20.f) ? za : log1pf(expf(za));
      decay[(size_t)row * H_ + h] = expf(-expf(A_log[h]) * sp);
    } else {
      beta[(size_t)row * H_ + h] = myval;
    }
  }
}

// ---------------------------------------------------------------------------
// Scan. Block = (dv-chunk c, head h, batch b), 256 threads.
// Lane owns 8 contiguous rows x 2 cols of the 128x32 state slice.
// sub = tid&15 (16 lanes per column group, DPP sum16 reductions),
// cp = tid>>4 (column pair; cols cp*2, cp*2+1 relative to chunk).
// k/q LDS layout: per timestep 32 float4 slots, phys = (d4&1)*16 + (d4>>1)
// so fragment reads lk4[u*32 + t*16 + sub] are 16 consecutive float4s.
// out_t = g*(q.s_prev) + (q.k)*delta  -- qk precomputed at staging time.
// ---------------------------------------------------------------------------
__global__ __launch_bounds__(256) void scan_kernel(
    const float* __restrict__ qg, const float* __restrict__ kg,
    const float* __restrict__ vg, const float* __restrict__ decay,
    const float* __restrict__ beta, float* __restrict__ outg) {
  const int c = blockIdx.x;
  const int h = blockIdx.y;
  const int b = blockIdx.z;
  const int tid = threadIdx.x;
  const int sub = tid & 15;
  const int cp = tid >> 4;

  __shared__ __align__(16) float lk[CH_ * DK_];
  __shared__ __align__(16) float lq[CH_ * DK_];
  __shared__ __align__(16) float lv[CH_ * COLS_];
  __shared__ __align__(16) float lgbq[CH_ * 4];  // (g, beta, qk, pad) per step

  const float4* k4 = reinterpret_cast<const float4*>(kg);
  const float4* q4 = reinterpret_cast<const float4*>(qg);
  const float4* v4 = reinterpret_cast<const float4*>(vg);
  float4* lk4 = reinterpret_cast<float4*>(lk);
  float4* lq4 = reinterpret_cast<float4*>(lq);
  float4* lv4 = reinterpret_cast<float4*>(lv);
  float2* lv2 = reinterpret_cast<float2*>(lv);

  // staging: thread stages k/q float4 (u0,d4) and (u1,d4)
  const int u0 = tid >> 5, d4 = tid & 31;
  const int u1 = 8 + u0;
  const int ph = (d4 & 1) * 16 + (d4 >> 1);

  float4 pk0 = {}, pk1 = {}, pq0 = {}, pq1 = {}, pv = {};
  float pg = 0.f, pb = 0.f;

  auto loadRegs = [&](int s0) {
    const size_t base0 = ((size_t)(b * S_ + s0 + u0) * H_ + h) * (DK_ / 4) + d4;
    const size_t base1 = ((size_t)(b * S_ + s0 + u1) * H_ + h) * (DK_ / 4) + d4;
    pk0 = k4[base0];
    pk1 = k4[base1];
    pq0 = q4[base0];
    pq1 = q4[base1];
    if (tid < 128) {
      const int uu = tid >> 3, e = tid & 7;
      pv = v4[((size_t)(b * S_ + s0 + uu) * H_ + h) * (DV_ / 4) + c * (COLS_ / 4) + e];
    }
    if (tid >= 128 && tid < 128 + CH_)
      pg = decay[(size_t)(b * S_ + s0 + (tid - 128)) * H_ + h];
    if (tid >= 160 && tid < 160 + CH_)
      pb = beta[(size_t)(b * S_ + s0 + (tid - 160)) * H_ + h];
  };

  auto writeLDS = [&]() {
    lk4[u0 * 32 + ph] = pk0;
    lk4[u1 * 32 + ph] = pk1;
    lq4[u0 * 32 + ph] = pq0;
    lq4[u1 * 32 + ph] = pq1;
    if (tid < 128) {
      const int uu = tid >> 3, e = tid & 7;
      lv4[uu * (COLS_ / 4) + e] = pv;
    }
    if (tid >= 128 && tid < 128 + CH_) lgbq[(tid - 128) * 4 + 0] = pg;
    if (tid >= 160 && tid < 160 + CH_) lgbq[(tid - 160) * 4 + 1] = pb;
    // qk[u] = q_u . k_u : per-lane dot4 partials reduced over the 32 lanes of u
    float p0 = fmaf(pq0.x, pk0.x, fmaf(pq0.y, pk0.y, fmaf(pq0.z, pk0.z, pq0.w * pk0.w)));
    float p1 = fmaf(pq1.x, pk1.x, fmaf(pq1.y, pk1.y, fmaf(pq1.z, pk1.z, pq1.w * pk1.w)));
    p0 = sum16(p0);
    p0 += swz_xor16(p0);
    p1 = sum16(p1);
    p1 += swz_xor16(p1);
    if ((tid & 31) == 0) {
      lgbq[u0 * 4 + 2] = p0;
      lgbq[u1 * 4 + 2] = p1;
    }
  };

  struct Frag {
    float4 k0, k1, q0, q1, gbq;
    float2 v;
  };
  auto loadFrag = [&](int u) {
    Frag f;
    f.k0 = lk4[u * 32 + sub];
    f.k1 = lk4[u * 32 + 16 + sub];
    f.q0 = lq4[u * 32 + sub];
    f.q1 = lq4[u * 32 + 16 + sub];
    f.v = lv2[u * (COLS_ / 2) + cp];
    f.gbq = *reinterpret_cast<const float4*>(&lgbq[u * 4]);
    return f;
  };

  float st[16];  // st[cc*8 + r]: col cp*2+cc, row sub*8+r
#pragma unroll
  for (int r = 0; r < 16; ++r) st[r] = 0.f;

  auto step = [&](const Frag& f, int u, int s0) {
    const float g = f.gbq.x, bt = f.gbq.y, qk = f.gbq.z;
    const float kr[8] = {f.k0.x, f.k0.y, f.k0.z, f.k0.w, f.k1.x, f.k1.y, f.k1.z, f.k1.w};
    const float qr[8] = {f.q0.x, f.q0.y, f.q0.z, f.q0.w, f.q1.x, f.q1.y, f.q1.z, f.q1.w};
    float vp0 = 0.f, vp1 = 0.f, op0 = 0.f, op1 = 0.f;
#pragma unroll
    for (int r = 0; r < 8; ++r) {
      vp0 = fmaf(kr[r], st[r], vp0);
      vp1 = fmaf(kr[r], st[8 + r], vp1);
      op0 = fmaf(qr[r], st[r], op0);
      op1 = fmaf(qr[r], st[8 + r], op1);
    }
    vp0 = sum16(vp0);
    vp1 = sum16(vp1);
    op0 = sum16(op0);
    op1 = sum16(op1);
    const float dlt0 = (f.v.x - g * vp0) * bt;
    const float dlt1 = (f.v.y - g * vp1) * bt;
#pragma unroll
    for (int r = 0; r < 8; ++r) {
      st[r] = fmaf(kr[r], dlt0, st[r] * g);
      st[8 + r] = fmaf(kr[r], dlt1, st[8 + r] * g);
    }
    if (sub == 0) {
      const float2 o = make_float2(fmaf(qk, dlt0, g * op0), fmaf(qk, dlt1, g * op1));
      *reinterpret_cast<float2*>(
          &outg[((size_t)(b * S_ + s0 + u) * H_ + h) * DV_ + c * COLS_ + cp * 2]) = o;
    }
  };

  loadRegs(0);
  writeLDS();
  __syncthreads();

  for (int ci = 0; ci < NCHS_; ++ci) {
    const int s0 = ci * CH_;
    if (ci + 1 < NCHS_) loadRegs(s0 + CH_);  // global prefetch for next chunk

    Frag cur = loadFrag(0);
    for (int u = 0; u < CH_ - 1; ++u) {
      Frag nxt = loadFrag(u + 1);  // LDS prefetch for next step
      step(cur, u, s0);
      cur = nxt;
    }
    step(cur, CH_ - 1, s0);

    __syncthreads();
    if (ci + 1 < NCHS_) writeLDS();
    __syncthreads();
  }
}

extern "C" void kernel_launch(void* const* d_in, const int* in_sizes, int n_in,
                              void* d_out, int out_size, void* d_ws, size_t ws_size,
                              hipStream_t stream) {
  const float* x = (const float*)d_in[0];
  const float* q = (const float*)d_in[1];
  const float* k = (const float*)d_in[2];
  const float* v = (const float*)d_in[3];
  const float* Wa = (const float*)d_in[4];
  const float* Wb = (const float*)d_in[5];
  const float* dtb = (const float*)d_in[6];
  const float* Alog = (const float*)d_in[7];
  float* out = (float*)d_out;

  float* decay = (float*)d_ws;
  float* beta = decay + (size_t)B_ * S_ * H_;

  gates_kernel<<<B_ * S_ / 4, 256, 0, stream>>>(x, Wa, Wb, dtb, Alog, decay, beta);
  scan_kernel<<<dim3(NC_, H_, B_), 256, 0, stream>>>(q, k, v, decay, beta, out);
}